// Round 1
// baseline (439.722 us; speedup 1.0000x reference)
//
#include <hip/hip_runtime.h>
#include <stdint.h>

#define NMS_T 0.7f
#define MINSZ 16.0f
#define NPRE 6000
#define NPOST 300
#define CAP 8192
#define NBIN 2048

// ---- workspace layout (bytes) ----
#define OFF_CAND   0                        // CAP * 8            = 65536
#define OFF_ROI    (OFF_CAND + CAP*8)       // NPRE * 16          = 96000
#define OFF_ORDER  (OFF_ROI + NPRE*16)      // NPRE * 4           = 24000
#define OFF_H1     (OFF_ORDER + NPRE*4)     // NBIN * 4           = 8192
#define OFF_H2     (OFF_H1 + NBIN*4)        // NBIN * 4           = 8192
#define OFF_SEL    (OFF_H2 + NBIN*4)        // 64
#define OFF_CNT    (OFF_SEL + 64)           // 16
#define OFF_KEYS   ((OFF_CNT + 16 + 255) & ~255)  // n * 4 (optional cache)

// descending-order sortable key: smaller inv == larger float
__device__ __forceinline__ unsigned inv_key(float s) {
    unsigned u = __float_as_uint(s);
    unsigned k = (u & 0x80000000u) ? ~u : (u | 0x80000000u); // ascending uint == ascending float
    return ~k;
}

// full decode (matches reference op-for-op)
__device__ __forceinline__ float4 decode_box(const float4 a, const float4 l,
                                             float ih, float iw) {
    float h  = a.z - a.x;
    float w  = a.w - a.y;
    float cy = a.x + 0.5f * h;
    float cx = a.y + 0.5f * w;
    float ncy = l.x * h + cy;
    float ncx = l.y * w + cx;
    float nh  = expf(l.z) * h;
    float nw  = expf(l.w) * w;
    float y1 = fminf(fmaxf(ncy - 0.5f * nh, 0.0f), ih);
    float x1 = fminf(fmaxf(ncx - 0.5f * nw, 0.0f), iw);
    float y2 = fminf(fmaxf(ncy + 0.5f * nh, 0.0f), ih);
    float x2 = fminf(fmaxf(ncx + 0.5f * nw, 0.0f), iw);
    return make_float4(y1, x1, y2, x2);
}

__device__ __forceinline__ unsigned decode_inv(const float4 a, const float4 l,
                                               float ih, float iw, float sc) {
    float4 r = decode_box(a, l, ih, iw);
    bool v = ((r.z - r.x) >= MINSZ) && ((r.w - r.y) >= MINSZ);
    float s = v ? sc : -__builtin_inff();
    return inv_key(s);
}

__global__ void k_init(unsigned* __restrict__ h1, unsigned* __restrict__ h2,
                       unsigned* __restrict__ cnt, unsigned* __restrict__ order) {
    int t = blockIdx.x * blockDim.x + threadIdx.x;
    if (t < NBIN) { h1[t] = 0; h2[t] = 0; }
    if (t == 0) cnt[0] = 0;
    if (t < NPRE) order[t] = 0xFFFFFFFFu;
}

__global__ void k_hist1(const float4* __restrict__ loc, const float* __restrict__ score,
                        const float4* __restrict__ anchor, const int* __restrict__ ph,
                        const int* __restrict__ pw, int n,
                        unsigned* __restrict__ hist1, unsigned* __restrict__ cache) {
    __shared__ unsigned lh[NBIN];
    for (int b = threadIdx.x; b < NBIN; b += blockDim.x) lh[b] = 0;
    __syncthreads();
    float ih = (float)ph[0], iw = (float)pw[0];
    int stride = gridDim.x * blockDim.x;
    for (int i = blockIdx.x * blockDim.x + threadIdx.x; i < n; i += stride) {
        unsigned inv = decode_inv(anchor[i], loc[i], ih, iw, score[i]);
        if (cache) cache[i] = inv;
        atomicAdd(&lh[inv >> 21], 1u);
    }
    __syncthreads();
    for (int b = threadIdx.x; b < NBIN; b += blockDim.x) {
        unsigned c = lh[b];
        if (c) atomicAdd(&hist1[b], c);
    }
}

__global__ void k_hist2(const float4* __restrict__ loc, const float* __restrict__ score,
                        const float4* __restrict__ anchor, const int* __restrict__ ph,
                        const int* __restrict__ pw, int n, const unsigned* __restrict__ sel_,
                        unsigned* __restrict__ hist2, const unsigned* __restrict__ cache) {
    __shared__ unsigned lh[NBIN];
    for (int b = threadIdx.x; b < NBIN; b += blockDim.x) lh[b] = 0;
    __syncthreads();
    unsigned B = sel_[0];
    float ih = (float)ph[0], iw = (float)pw[0];
    int stride = gridDim.x * blockDim.x;
    for (int i = blockIdx.x * blockDim.x + threadIdx.x; i < n; i += stride) {
        unsigned inv = cache ? cache[i] : decode_inv(anchor[i], loc[i], ih, iw, score[i]);
        if ((inv >> 21) == B) atomicAdd(&lh[(inv >> 10) & (NBIN - 1)], 1u);
    }
    __syncthreads();
    for (int b = threadIdx.x; b < NBIN; b += blockDim.x) {
        unsigned c = lh[b];
        if (c) atomicAdd(&hist2[b], c);
    }
}

// phase 0: find level-1 bin B containing the NPRE-th key; phase 1: level-2 sub-bin
__global__ void k_scan(const unsigned* __restrict__ hist, unsigned* sel_, int phase) {
    __shared__ unsigned psum[256];
    int t = threadIdx.x;
    unsigned target = (phase == 0) ? (unsigned)NPRE : ((unsigned)NPRE - sel_[1]);
    unsigned vals[8];
    unsigned s = 0;
#pragma unroll
    for (int j = 0; j < 8; j++) { vals[j] = hist[t * 8 + j]; s += vals[j]; }
    psum[t] = s;
    __syncthreads();
    for (int off = 1; off < 256; off <<= 1) {
        unsigned v = (t >= off) ? psum[t - off] : 0u;
        __syncthreads();
        psum[t] += v;
        __syncthreads();
    }
    unsigned run = (t == 0) ? 0u : psum[t - 1];
#pragma unroll
    for (int j = 0; j < 8; j++) {
        unsigned c = vals[j];
        if (run < target && run + c >= target) {
            if (phase == 0) { sel_[0] = (unsigned)(t * 8 + j); sel_[1] = run; }
            else            { sel_[2] = sel_[0] * (unsigned)NBIN + (unsigned)(t * 8 + j); }
        }
        run += c;
    }
}

__global__ void k_compact(const float4* __restrict__ loc, const float* __restrict__ score,
                          const float4* __restrict__ anchor, const int* __restrict__ ph,
                          const int* __restrict__ pw, int n, const unsigned* __restrict__ sel_,
                          unsigned long long* __restrict__ cand, unsigned* __restrict__ cnt,
                          const unsigned* __restrict__ cache) {
    unsigned TH = sel_[2];
    float ih = (float)ph[0], iw = (float)pw[0];
    int stride = gridDim.x * blockDim.x;
    for (int i = blockIdx.x * blockDim.x + threadIdx.x; i < n; i += stride) {
        unsigned inv = cache ? cache[i] : decode_inv(anchor[i], loc[i], ih, iw, score[i]);
        if ((inv >> 10) <= TH) {
            unsigned p = atomicAdd(cnt, 1u);
            if (p < CAP) cand[p] = ((unsigned long long)inv << 32) | (unsigned)i;
        }
    }
}

// exact global rank of each candidate (keys unique since index is embedded)
__global__ void k_rank(const unsigned long long* __restrict__ cand,
                       const unsigned* __restrict__ cnt, unsigned* __restrict__ order) {
    __shared__ unsigned long long lk[CAP];
    int M = (int)min(*cnt, (unsigned)CAP);
    for (int i = threadIdx.x; i < CAP; i += blockDim.x)
        lk[i] = (i < M) ? cand[i] : ~0ULL;
    __syncthreads();
    int c = blockIdx.x * blockDim.x + threadIdx.x;
    if (c < M) {
        unsigned long long key = lk[c];
        int rank = 0;
#pragma unroll 4
        for (int j = 0; j < M; j++) rank += (lk[j] < key) ? 1 : 0;
        if (rank < NPRE) order[rank] = (unsigned)(key & 0xFFFFFFFFu);
    }
}

__global__ void k_build(const float4* __restrict__ loc, const float4* __restrict__ anchor,
                        const int* __restrict__ ph, const int* __restrict__ pw,
                        const unsigned* __restrict__ order, float4* __restrict__ roi, int n) {
    int r = blockIdx.x * blockDim.x + threadIdx.x;
    if (r >= NPRE) return;
    unsigned idx = order[r];
    float4 box = make_float4(0.f, 0.f, 0.f, 0.f);  // zero box: hs=0<16 -> treated invalid
    if (idx < (unsigned)n) {
        float ih = (float)ph[0], iw = (float)pw[0];
        box = decode_box(anchor[idx], loc[idx], ih, iw);
    }
    roi[r] = box;
}

// single-wave greedy NMS with exact early-exit at 300 kept
__global__ void __launch_bounds__(64) k_nms(const float4* __restrict__ roi,
                                            float* __restrict__ out) {
    __shared__ float4 sroi[NPRE];                         // 96 KB
    __shared__ float ky1[NPOST], kx1[NPOST], ky2[NPOST], kx2[NPOST], kar[NPOST];
    int lane = threadIdx.x;
    for (int i = lane; i < NPRE; i += 64) sroi[i] = roi[i];
    __syncthreads();
    int nk = 0;
    for (int i = 0; i < NPRE; i++) {
        float4 b = sroi[i];
        float hs = b.z - b.x, ws_ = b.w - b.y;
        if (!(hs >= MINSZ && ws_ >= MINSZ)) continue;     // invalid: never kept, never suppresses
        float ab = hs * ws_;
        bool sup = false;
        for (int base = 0; base < nk && !sup; base += 64) {
            int t = base + lane;
            bool s = false;
            if (t < nk) {
                float yy1 = fmaxf(b.x, ky1[t]);
                float xx1 = fmaxf(b.y, kx1[t]);
                float yy2 = fminf(b.z, ky2[t]);
                float xx2 = fminf(b.w, kx2[t]);
                float inter = fmaxf(yy2 - yy1, 0.0f) * fmaxf(xx2 - xx1, 0.0f);
                float iou = inter / (kar[t] + ab - inter); // same IEEE div as reference
                s = iou > NMS_T;
            }
            sup = (__ballot(s) != 0ULL);
        }
        if (!sup) {
            if (lane == 0) { ky1[nk] = b.x; kx1[nk] = b.y; ky2[nk] = b.z; kx2[nk] = b.w; kar[nk] = ab; }
            __syncthreads();
            nk++;
            if (nk == NPOST) break;                       // exact: suppression only flows forward
        }
    }
    for (int k = lane; k < NPOST; k += 64) {
        float4 o = make_float4(0.f, 0.f, 0.f, 0.f);
        if (k < nk) o = make_float4(ky1[k], kx1[k], ky2[k], kx2[k]);
        reinterpret_cast<float4*>(out)[k] = o;
    }
}

extern "C" void kernel_launch(void* const* d_in, const int* in_sizes, int n_in,
                              void* d_out, int out_size, void* d_ws, size_t ws_size,
                              hipStream_t stream) {
    const float4* loc    = (const float4*)d_in[0];
    const float*  score  = (const float*)d_in[1];
    const float4* anchor = (const float4*)d_in[2];
    const int*    ph     = (const int*)d_in[3];
    const int*    pw     = (const int*)d_in[4];
    int n = in_sizes[1];

    char* ws = (char*)d_ws;
    unsigned long long* cand = (unsigned long long*)(ws + OFF_CAND);
    float4*   roi   = (float4*)(ws + OFF_ROI);
    unsigned* order = (unsigned*)(ws + OFF_ORDER);
    unsigned* h1    = (unsigned*)(ws + OFF_H1);
    unsigned* h2    = (unsigned*)(ws + OFF_H2);
    unsigned* sel   = (unsigned*)(ws + OFF_SEL);
    unsigned* cnt   = (unsigned*)(ws + OFF_CNT);
    unsigned* cache = nullptr;
    if (ws_size >= (size_t)OFF_KEYS + (size_t)n * 4) cache = (unsigned*)(ws + OFF_KEYS);

    float* out = (float*)d_out;

    k_init<<<dim3(24), dim3(256), 0, stream>>>(h1, h2, cnt, order);
    k_hist1<<<dim3(512), dim3(256), 0, stream>>>(loc, score, anchor, ph, pw, n, h1, cache);
    k_scan<<<dim3(1), dim3(256), 0, stream>>>(h1, sel, 0);
    k_hist2<<<dim3(512), dim3(256), 0, stream>>>(loc, score, anchor, ph, pw, n, sel, h2, cache);
    k_scan<<<dim3(1), dim3(256), 0, stream>>>(h2, sel, 1);
    k_compact<<<dim3(512), dim3(256), 0, stream>>>(loc, score, anchor, ph, pw, n, sel, cand, cnt, cache);
    k_rank<<<dim3(CAP / 256), dim3(256), 0, stream>>>(cand, cnt, order);
    k_build<<<dim3((NPRE + 255) / 256), dim3(256), 0, stream>>>(loc, anchor, ph, pw, order, roi, n);
    k_nms<<<dim3(1), dim3(64), 0, stream>>>(roi, out);
}

// Round 2
// 207.679 us; speedup vs baseline: 2.1173x; 2.1173x over previous
//
#include <hip/hip_runtime.h>
#include <stdint.h>

typedef unsigned long long u64;

#define NMS_T 0.7f
#define MINSZ 16.0f
#define NPRE 6000
#define NPOST 300
#define CA   1024      // matrix candidate count (common path)
#define CAPA 2048
#define CAP6 8192
#define NBIN 2048

// ---- workspace layout (bytes) ----
#define OFF_CAND6  0                              // CAP6*8 = 65536
#define OFF_CANDA  (OFF_CAND6 + CAP6*8)           // CAPA*8 = 16384
#define OFF_ORDERA (OFF_CANDA + CAPA*8)           // CA*4   = 4096
#define OFF_ORDER6 (OFF_ORDERA + CA*4)            // NPRE*4 = 24000 (fallback)
#define OFF_ROI6   (OFF_ORDER6 + NPRE*4)          // NPRE*16 = 96000 (fallback)
#define OFF_H1     (OFF_ROI6 + NPRE*16)           // NBIN*4
#define OFF_H2A    (OFF_H1 + NBIN*4)              // NBIN*4
#define OFF_H2B    (OFF_H2A + NBIN*4)             // NBIN*4
#define OFF_SEL    (OFF_H2B + NBIN*4)             // 64
#define OFF_CNT    (OFF_SEL + 64)                 // 16: [0]=cntA [1]=cnt6 [2]=flag
#define OFF_GMAT   ((OFF_CNT + 16 + 255) & ~255)  // CA*16*8 = 131072
#define OFF_KEYS   ((OFF_GMAT + CA*16*8 + 255) & ~255)  // n*4 key cache

// descending-order sortable key: smaller inv == larger float
__device__ __forceinline__ unsigned inv_key(float s) {
    unsigned u = __float_as_uint(s);
    unsigned k = (u & 0x80000000u) ? ~u : (u | 0x80000000u);
    return ~k;
}

__device__ __forceinline__ float4 decode_box(const float4 a, const float4 l,
                                             float ih, float iw) {
    float h  = a.z - a.x;
    float w  = a.w - a.y;
    float cy = a.x + 0.5f * h;
    float cx = a.y + 0.5f * w;
    float ncy = l.x * h + cy;
    float ncx = l.y * w + cx;
    float nh  = expf(l.z) * h;
    float nw  = expf(l.w) * w;
    float y1 = fminf(fmaxf(ncy - 0.5f * nh, 0.0f), ih);
    float x1 = fminf(fmaxf(ncx - 0.5f * nw, 0.0f), iw);
    float y2 = fminf(fmaxf(ncy + 0.5f * nh, 0.0f), ih);
    float x2 = fminf(fmaxf(ncx + 0.5f * nw, 0.0f), iw);
    return make_float4(y1, x1, y2, x2);
}

__device__ __forceinline__ unsigned decode_inv(const float4 a, const float4 l,
                                               float ih, float iw, float sc) {
    float4 r = decode_box(a, l, ih, iw);
    bool v = ((r.z - r.x) >= MINSZ) && ((r.w - r.y) >= MINSZ);
    float s = v ? sc : -__builtin_inff();
    return inv_key(s);
}

__global__ void k_init(unsigned* __restrict__ h1, unsigned* __restrict__ h2a,
                       unsigned* __restrict__ h2b, unsigned* __restrict__ cnts,
                       unsigned* __restrict__ orderA) {
    int t = blockIdx.x * blockDim.x + threadIdx.x;
    if (t < NBIN) { h1[t] = 0; h2a[t] = 0; h2b[t] = 0; }
    if (t < CA) orderA[t] = 0xFFFFFFFFu;
    if (t < 4) cnts[t] = 0;
}

__global__ void k_hist1(const float4* __restrict__ loc, const float* __restrict__ score,
                        const float4* __restrict__ anchor, const int* __restrict__ ph,
                        const int* __restrict__ pw, int n,
                        unsigned* __restrict__ hist1, unsigned* __restrict__ cache) {
    __shared__ unsigned lh[NBIN];
    for (int b = threadIdx.x; b < NBIN; b += blockDim.x) lh[b] = 0;
    __syncthreads();
    float ih = (float)ph[0], iw = (float)pw[0];
    int stride = gridDim.x * blockDim.x;
    for (int i = blockIdx.x * blockDim.x + threadIdx.x; i < n; i += stride) {
        unsigned inv = decode_inv(anchor[i], loc[i], ih, iw, score[i]);
        if (cache) cache[i] = inv;
        atomicAdd(&lh[inv >> 21], 1u);
    }
    __syncthreads();
    for (int b = threadIdx.x; b < NBIN; b += blockDim.x) {
        unsigned c = lh[b];
        if (c) atomicAdd(&hist1[b], c);
    }
}

// two targets on level-1 histogram: CA and NPRE
__global__ void k_scanA(const unsigned* __restrict__ h1, unsigned* sel_) {
    __shared__ unsigned psum[256];
    int t = threadIdx.x;
    unsigned vals[8];
    unsigned s = 0;
#pragma unroll
    for (int j = 0; j < 8; j++) { vals[j] = h1[t * 8 + j]; s += vals[j]; }
    psum[t] = s;
    __syncthreads();
    for (int off = 1; off < 256; off <<= 1) {
        unsigned v = (t >= off) ? psum[t - off] : 0u;
        __syncthreads();
        psum[t] += v;
        __syncthreads();
    }
    unsigned run = (t == 0) ? 0u : psum[t - 1];
#pragma unroll
    for (int j = 0; j < 8; j++) {
        unsigned c = vals[j];
        if (run < (unsigned)CA && run + c >= (unsigned)CA)     { sel_[0] = t * 8 + j; sel_[1] = run; }
        if (run < (unsigned)NPRE && run + c >= (unsigned)NPRE) { sel_[4] = t * 8 + j; sel_[5] = run; }
        run += c;
    }
}

__global__ void k_hist2(const float4* __restrict__ loc, const float* __restrict__ score,
                        const float4* __restrict__ anchor, const int* __restrict__ ph,
                        const int* __restrict__ pw, int n, const unsigned* __restrict__ sel_,
                        unsigned* __restrict__ h2a, unsigned* __restrict__ h2b,
                        const unsigned* __restrict__ cache) {
    __shared__ unsigned lha[NBIN];
    __shared__ unsigned lhb[NBIN];
    for (int b = threadIdx.x; b < NBIN; b += blockDim.x) { lha[b] = 0; lhb[b] = 0; }
    __syncthreads();
    unsigned binA = sel_[0], bin6 = sel_[4];
    float ih = (float)ph[0], iw = (float)pw[0];
    int stride = gridDim.x * blockDim.x;
    for (int i = blockIdx.x * blockDim.x + threadIdx.x; i < n; i += stride) {
        unsigned inv = cache ? cache[i] : decode_inv(anchor[i], loc[i], ih, iw, score[i]);
        unsigned top = inv >> 21;
        if (top == binA) atomicAdd(&lha[(inv >> 10) & (NBIN - 1)], 1u);
        if (top == bin6) atomicAdd(&lhb[(inv >> 10) & (NBIN - 1)], 1u);
    }
    __syncthreads();
    for (int b = threadIdx.x; b < NBIN; b += blockDim.x) {
        unsigned ca = lha[b], cb = lhb[b];
        if (ca) atomicAdd(&h2a[b], ca);
        if (cb) atomicAdd(&h2b[b], cb);
    }
}

// level-2 thresholds for both targets: sel[2]=TH_A, sel[6]=TH_6
__global__ void k_scan2(const unsigned* __restrict__ h2a, const unsigned* __restrict__ h2b,
                        unsigned* sel_) {
    __shared__ unsigned psum[256];
    int t = threadIdx.x;
    for (int pass = 0; pass < 2; ++pass) {
        const unsigned* h = pass ? h2b : h2a;
        unsigned target = pass ? ((unsigned)NPRE - sel_[5]) : ((unsigned)CA - sel_[1]);
        unsigned topbin = pass ? sel_[4] : sel_[0];
        unsigned vals[8];
        unsigned s = 0;
#pragma unroll
        for (int j = 0; j < 8; j++) { vals[j] = h[t * 8 + j]; s += vals[j]; }
        psum[t] = s;
        __syncthreads();
        for (int off = 1; off < 256; off <<= 1) {
            unsigned v = (t >= off) ? psum[t - off] : 0u;
            __syncthreads();
            psum[t] += v;
            __syncthreads();
        }
        unsigned run = (t == 0) ? 0u : psum[t - 1];
#pragma unroll
        for (int j = 0; j < 8; j++) {
            unsigned c = vals[j];
            if (run < target && run + c >= target)
                sel_[pass ? 6 : 2] = topbin * (unsigned)NBIN + (unsigned)(t * 8 + j);
            run += c;
        }
        __syncthreads();
    }
}

__global__ void k_compact(const float4* __restrict__ loc, const float* __restrict__ score,
                          const float4* __restrict__ anchor, const int* __restrict__ ph,
                          const int* __restrict__ pw, int n, const unsigned* __restrict__ sel_,
                          u64* __restrict__ candA, u64* __restrict__ cand6,
                          unsigned* __restrict__ cnts, const unsigned* __restrict__ cache) {
    unsigned THA = sel_[2], TH6 = sel_[6];
    float ih = (float)ph[0], iw = (float)pw[0];
    int stride = gridDim.x * blockDim.x;
    for (int i = blockIdx.x * blockDim.x + threadIdx.x; i < n; i += stride) {
        unsigned inv = cache ? cache[i] : decode_inv(anchor[i], loc[i], ih, iw, score[i]);
        unsigned pre = inv >> 10;
        if (pre <= TH6) {
            u64 key = ((u64)inv << 32) | (unsigned)i;
            unsigned p = atomicAdd(&cnts[1], 1u);
            if (p < CAP6) cand6[p] = key;
            if (pre <= THA) {
                unsigned q = atomicAdd(&cnts[0], 1u);
                if (q < CAPA) candA[q] = key;
            }
        }
    }
}

// exact global ranks of top-CA candidates (candA is prefix-closed in global order)
__global__ void k_rankA(const u64* __restrict__ candA, const unsigned* __restrict__ cnts,
                        unsigned* __restrict__ orderA) {
    __shared__ u64 lk[CAPA];
    int tid = threadIdx.x;
    int MA = (int)min(cnts[0], (unsigned)CAPA);
    for (int i = tid; i < CAPA; i += 256) lk[i] = (i < MA) ? candA[i] : ~0ULL;
    __syncthreads();
    int c = blockIdx.x * 256 + tid;
    if (c < MA) {
        u64 key = lk[c];
        int rank = 0;
#pragma unroll 8
        for (int j = 0; j < MA; ++j) rank += (lk[j] < key) ? 1 : 0;
        if (rank < CA) orderA[rank] = (unsigned)(key & 0xFFFFFFFFu);
    }
}

// suppression bit-matrix for top-CA candidates: bit j of word w of row i
__global__ void __launch_bounds__(256) k_mat(
        const float4* __restrict__ loc, const float4* __restrict__ anchor,
        const int* __restrict__ ph, const int* __restrict__ pw,
        const unsigned* __restrict__ orderA, u64* __restrict__ gmat, int n) {
    __shared__ float4 sroi[CA];
    __shared__ float sarea[CA];
    int tid = threadIdx.x;
    float ih = (float)ph[0], iw = (float)pw[0];
    for (int r = tid; r < CA; r += 256) {
        unsigned idx = orderA[r];
        float4 b = make_float4(0.f, 0.f, 0.f, 0.f);
        if (idx < (unsigned)n) b = decode_box(anchor[idx], loc[idx], ih, iw);
        sroi[r] = b;
        sarea[r] = (b.z - b.x) * (b.w - b.y);
    }
    __syncthreads();
    int row = blockIdx.x * 16 + (tid >> 4);
    int w   = tid & 15;
    float4 b = sroi[row];
    float ab = sarea[row];
    u64 bits = 0;
    int j0 = w * 64;
#pragma unroll 4
    for (int jj = 0; jj < 64; ++jj) {
        int j = j0 + jj;
        if (j > row) {
            float4 c = sroi[j];
            float yy1 = fmaxf(b.x, c.x);
            float xx1 = fmaxf(b.y, c.y);
            float yy2 = fminf(b.z, c.z);
            float xx2 = fminf(b.w, c.w);
            float inter = fmaxf(yy2 - yy1, 0.0f) * fmaxf(xx2 - xx1, 0.0f);
            float iou = inter / (ab + sarea[j] - inter);  // same op order as reference
            if (iou > NMS_T) bits |= (1ULL << jj);
        }
    }
    gmat[(size_t)row * 16 + w] = bits;
}

// serial scan over bitmask matrix; breaks at 300 kept (exact: suppression flows forward only)
__global__ void __launch_bounds__(256) k_scan_nms(
        const float4* __restrict__ loc, const float4* __restrict__ anchor,
        const int* __restrict__ ph, const int* __restrict__ pw,
        const unsigned* __restrict__ orderA, const u64* __restrict__ gmat,
        unsigned* __restrict__ cnts, float* __restrict__ out, int n) {
    __shared__ u64 smat[CA * 16];     // 128 KB
    __shared__ float4 sroi[CA];       // 16 KB
    __shared__ unsigned ssup[32];     // initial suppressed bits (invalid boxes)
    __shared__ unsigned skept[NPOST];
    int tid = threadIdx.x;
    if (tid < 32) ssup[tid] = 0;
    __syncthreads();
    float ih = (float)ph[0], iw = (float)pw[0];
    for (int r = tid; r < CA; r += 256) {
        unsigned idx = orderA[r];
        float4 b = make_float4(0.f, 0.f, 0.f, 0.f);
        if (idx < (unsigned)n) b = decode_box(anchor[idx], loc[idx], ih, iw);
        sroi[r] = b;
        bool valid = ((b.z - b.x) >= MINSZ) && ((b.w - b.y) >= MINSZ);
        if (!valid) atomicOr(&ssup[r >> 5], 1u << (r & 31));
    }
    {   // stage matrix 128 KB, vectorized
        const float4* gm4 = (const float4*)gmat;
        float4* sm4 = (float4*)smat;
        for (int k = tid; k < CA * 16 * 8 / 16; k += 256) sm4[k] = gm4[k];
    }
    __syncthreads();
    if (tid >= 64) return;
    int lane = tid, w = lane & 15;
    u64 sup = ((u64)ssup[2 * w + 1] << 32) | (u64)ssup[2 * w];
    int Ceff = (int)min((unsigned)CA, cnts[0]);
    int nk = 0;
    u64 r0 = smat[0 * 16 + w];
    u64 r1 = smat[1 * 16 + w];
    for (int i = 0; i < Ceff; ++i) {
        u64 r2 = (i + 2 < CA) ? smat[(i + 2) * 16 + w] : 0ULL;   // 2-deep prefetch
        bool supbit = (lane == (i >> 6)) && ((sup >> (i & 63)) & 1ULL);
        if (__ballot(supbit) == 0ULL) {
            if (lane == 0) skept[nk] = (unsigned)i;
            sup |= r0;
            ++nk;
            if (nk == NPOST) break;
        }
        r0 = r1; r1 = r2;
    }
    float4* out4 = (float4*)out;
    for (int k = lane; k < NPOST; k += 64) {
        float4 o = make_float4(0.f, 0.f, 0.f, 0.f);
        if (k < nk) o = sroi[skept[k]];
        out4[k] = o;
    }
    if (lane == 0) cnts[2] = (nk < NPOST && cnts[1] > (unsigned)Ceff) ? 1u : 0u;
}

// flag-gated exact fallback: full 6000 rank + serial NMS. Never runs on sane data.
__global__ void __launch_bounds__(256) k_fb(
        const float4* __restrict__ loc, const float4* __restrict__ anchor,
        const int* __restrict__ ph, const int* __restrict__ pw,
        const u64* __restrict__ cand6, const unsigned* __restrict__ cnts,
        unsigned* __restrict__ order6, float4* __restrict__ roi6,
        float* __restrict__ out, int n) {
    if (cnts[2] == 0) return;
    __shared__ u64 lk[CAP6];          // 64 KB
    __shared__ float ky1[NPOST], kx1[NPOST], ky2[NPOST], kx2[NPOST], kar[NPOST];
    int tid = threadIdx.x;
    int M = (int)min(cnts[1], (unsigned)CAP6);
    for (int i = tid; i < CAP6; i += 256) lk[i] = (i < M) ? cand6[i] : ~0ULL;
    for (int r = tid; r < NPRE; r += 256) order6[r] = 0xFFFFFFFFu;
    __syncthreads();
    for (int c = tid; c < M; c += 256) {
        u64 key = lk[c];
        int rank = 0;
        for (int j = 0; j < M; ++j) rank += (lk[j] < key) ? 1 : 0;
        if (rank < NPRE) order6[rank] = (unsigned)(key & 0xFFFFFFFFu);
    }
    __syncthreads();
    float ih = (float)ph[0], iw = (float)pw[0];
    for (int r = tid; r < NPRE; r += 256) {
        unsigned idx = order6[r];
        float4 b = make_float4(0.f, 0.f, 0.f, 0.f);
        if (idx < (unsigned)n) b = decode_box(anchor[idx], loc[idx], ih, iw);
        roi6[r] = b;
    }
    __syncthreads();
    if (tid >= 64) return;
    int lane = tid;
    int nk = 0;
    for (int i = 0; i < NPRE; i++) {
        float4 b = roi6[i];
        float hs = b.z - b.x, wd = b.w - b.y;
        if (!(hs >= MINSZ && wd >= MINSZ)) continue;
        float ab = hs * wd;
        bool sup = false;
        for (int base = 0; base < nk && !sup; base += 64) {
            int t = base + lane;
            bool s = false;
            if (t < nk) {
                float yy1 = fmaxf(b.x, ky1[t]);
                float xx1 = fmaxf(b.y, kx1[t]);
                float yy2 = fminf(b.z, ky2[t]);
                float xx2 = fminf(b.w, kx2[t]);
                float inter = fmaxf(yy2 - yy1, 0.0f) * fmaxf(xx2 - xx1, 0.0f);
                float iou = inter / (kar[t] + ab - inter);
                s = iou > NMS_T;
            }
            sup = (__ballot(s) != 0ULL);
        }
        if (!sup) {
            if (lane == 0) { ky1[nk] = b.x; kx1[nk] = b.y; ky2[nk] = b.z; kx2[nk] = b.w; kar[nk] = ab; }
            nk++;
            if (nk == NPOST) break;
        }
    }
    for (int k = lane; k < NPOST; k += 64) {
        float4 o = make_float4(0.f, 0.f, 0.f, 0.f);
        if (k < nk) o = make_float4(ky1[k], kx1[k], ky2[k], kx2[k]);
        reinterpret_cast<float4*>(out)[k] = o;
    }
}

extern "C" void kernel_launch(void* const* d_in, const int* in_sizes, int n_in,
                              void* d_out, int out_size, void* d_ws, size_t ws_size,
                              hipStream_t stream) {
    const float4* loc    = (const float4*)d_in[0];
    const float*  score  = (const float*)d_in[1];
    const float4* anchor = (const float4*)d_in[2];
    const int*    ph     = (const int*)d_in[3];
    const int*    pw     = (const int*)d_in[4];
    int n = in_sizes[1];

    char* ws = (char*)d_ws;
    u64*      cand6  = (u64*)(ws + OFF_CAND6);
    u64*      candA  = (u64*)(ws + OFF_CANDA);
    unsigned* orderA = (unsigned*)(ws + OFF_ORDERA);
    unsigned* order6 = (unsigned*)(ws + OFF_ORDER6);
    float4*   roi6   = (float4*)(ws + OFF_ROI6);
    unsigned* h1     = (unsigned*)(ws + OFF_H1);
    unsigned* h2a    = (unsigned*)(ws + OFF_H2A);
    unsigned* h2b    = (unsigned*)(ws + OFF_H2B);
    unsigned* sel    = (unsigned*)(ws + OFF_SEL);
    unsigned* cnts   = (unsigned*)(ws + OFF_CNT);
    u64*      gmat   = (u64*)(ws + OFF_GMAT);
    unsigned* cache  = nullptr;
    if (ws_size >= (size_t)OFF_KEYS + (size_t)n * 4) cache = (unsigned*)(ws + OFF_KEYS);

    float* out = (float*)d_out;

    k_init   <<<dim3(8),   dim3(256), 0, stream>>>(h1, h2a, h2b, cnts, orderA);
    k_hist1  <<<dim3(512), dim3(256), 0, stream>>>(loc, score, anchor, ph, pw, n, h1, cache);
    k_scanA  <<<dim3(1),   dim3(256), 0, stream>>>(h1, sel);
    k_hist2  <<<dim3(512), dim3(256), 0, stream>>>(loc, score, anchor, ph, pw, n, sel, h2a, h2b, cache);
    k_scan2  <<<dim3(1),   dim3(256), 0, stream>>>(h2a, h2b, sel);
    k_compact<<<dim3(512), dim3(256), 0, stream>>>(loc, score, anchor, ph, pw, n, sel, candA, cand6, cnts, cache);
    k_rankA  <<<dim3(CAPA / 256), dim3(256), 0, stream>>>(candA, cnts, orderA);
    k_mat    <<<dim3(CA / 16),    dim3(256), 0, stream>>>(loc, anchor, ph, pw, orderA, gmat, n);
    k_scan_nms<<<dim3(1),  dim3(256), 0, stream>>>(loc, anchor, ph, pw, orderA, gmat, cnts, out, n);
    k_fb     <<<dim3(1),   dim3(256), 0, stream>>>(loc, anchor, ph, pw, cand6, cnts, order6, roi6, out, n);
}

// Round 3
// 130.710 us; speedup vs baseline: 3.3641x; 1.5889x over previous
//
#include <hip/hip_runtime.h>
#include <stdint.h>

typedef unsigned long long u64;

#define NMS_T 0.7f
#define MINSZ 16.0f
#define NPRE 6000
#define NPOST 300
#define CA   512       // matrix candidate count (common path; NMS breaks at 300 kept ~ i=310)
#define CAPA 1024
#define CAP6 8192
#define NBIN 2048

// ---- workspace layout (bytes) ----
#define OFF_CAND6  0                              // CAP6*8 = 65536
#define OFF_CANDA  (OFF_CAND6 + CAP6*8)           // CAPA*8 = 8192
#define OFF_ORDERA (OFF_CANDA + CAPA*8)           // CA*4   = 2048
#define OFF_ORDER6 (OFF_ORDERA + CA*4)            // NPRE*4 = 24000 (fallback)
#define OFF_ROI6   (OFF_ORDER6 + NPRE*4)          // NPRE*16 = 96000 (fallback)
#define OFF_H1     (OFF_ROI6 + NPRE*16)           // NBIN*4
#define OFF_H2A    (OFF_H1 + NBIN*4)              // NBIN*4
#define OFF_H2B    (OFF_H2A + NBIN*4)             // NBIN*4
#define OFF_CNT    (OFF_H2B + NBIN*4)             // 16: [0]=cntA [1]=cnt6 [2]=flag
#define OFF_ZEND   (OFF_CNT + 16)
#define OFF_GMAT   ((OFF_ZEND + 255) & ~255)      // CA*8*8 = 32768
#define OFF_KEYS   ((OFF_GMAT + CA*8*8 + 255) & ~255)   // n*4 key cache

// descending-order sortable key: smaller inv == larger float
__device__ __forceinline__ unsigned inv_key(float s) {
    unsigned u = __float_as_uint(s);
    unsigned k = (u & 0x80000000u) ? ~u : (u | 0x80000000u);
    return ~k;
}

__device__ __forceinline__ float4 decode_box(const float4 a, const float4 l,
                                             float ih, float iw) {
    float h  = a.z - a.x;
    float w  = a.w - a.y;
    float cy = a.x + 0.5f * h;
    float cx = a.y + 0.5f * w;
    float ncy = l.x * h + cy;
    float ncx = l.y * w + cx;
    float nh  = expf(l.z) * h;
    float nw  = expf(l.w) * w;
    float y1 = fminf(fmaxf(ncy - 0.5f * nh, 0.0f), ih);
    float x1 = fminf(fmaxf(ncx - 0.5f * nw, 0.0f), iw);
    float y2 = fminf(fmaxf(ncy + 0.5f * nh, 0.0f), ih);
    float x2 = fminf(fmaxf(ncx + 0.5f * nw, 0.0f), iw);
    return make_float4(y1, x1, y2, x2);
}

__device__ __forceinline__ unsigned decode_inv(const float4 a, const float4 l,
                                               float ih, float iw, float sc) {
    float4 r = decode_box(a, l, ih, iw);
    bool v = ((r.z - r.x) >= MINSZ) && ((r.w - r.y) >= MINSZ);
    float s = v ? sc : -__builtin_inff();
    return inv_key(s);
}

// block-wide (256 threads) scan of a 2048-bin histogram; finds bins containing
// ranks t0 and (optionally) t1. Results into res[base..]: {bin0, run0, bin1, run1}.
__device__ void scan2048(const unsigned* __restrict__ h, unsigned t0, unsigned t1,
                         unsigned* psum, unsigned* res, int base) {
    int t = threadIdx.x;
    unsigned vals[8];
    unsigned s = 0;
#pragma unroll
    for (int j = 0; j < 8; j++) { vals[j] = h[t * 8 + j]; s += vals[j]; }
    psum[t] = s;
    __syncthreads();
    for (int off = 1; off < 256; off <<= 1) {
        unsigned v = (t >= off) ? psum[t - off] : 0u;
        __syncthreads();
        psum[t] += v;
        __syncthreads();
    }
    unsigned run = (t == 0) ? 0u : psum[t - 1];
#pragma unroll
    for (int j = 0; j < 8; j++) {
        unsigned c = vals[j];
        if (run < t0 && run + c >= t0) { res[base + 0] = t * 8 + j; res[base + 1] = run; }
        if (t1 && run < t1 && run + c >= t1) { res[base + 2] = t * 8 + j; res[base + 3] = run; }
        run += c;
    }
    __syncthreads();
}

__global__ void k_init(unsigned* __restrict__ zbase, unsigned* __restrict__ orderA) {
    int t = blockIdx.x * blockDim.x + threadIdx.x;
    int nz = (OFF_ZEND - OFF_H1) / 4;
    if (t < nz) zbase[t] = 0;
    if (t < CA) orderA[t] = 0xFFFFFFFFu;
}

__global__ void __launch_bounds__(256) k_hist1(
        const float4* __restrict__ loc, const float* __restrict__ score,
        const float4* __restrict__ anchor, const int* __restrict__ ph,
        const int* __restrict__ pw, int n,
        unsigned* __restrict__ hist1, unsigned* __restrict__ cache) {
    __shared__ unsigned lh[NBIN];
    for (int b = threadIdx.x; b < NBIN; b += 256) lh[b] = 0;
    __syncthreads();
    float ih = (float)ph[0], iw = (float)pw[0];
    int stride = gridDim.x * 256;
    for (int i = blockIdx.x * 256 + threadIdx.x; i < n; i += stride) {
        unsigned inv = decode_inv(anchor[i], loc[i], ih, iw, score[i]);
        if (cache) cache[i] = inv;
        atomicAdd(&lh[inv >> 21], 1u);
    }
    __syncthreads();
    for (int b = threadIdx.x; b < NBIN; b += 256) {
        unsigned c = lh[b];
        if (c) atomicAdd(&hist1[b], c);
    }
}

// prologue: re-derive level-1 bins for targets CA and NPRE from h1, then histogram level-2
__global__ void __launch_bounds__(256) k_hist2(
        const float4* __restrict__ loc, const float* __restrict__ score,
        const float4* __restrict__ anchor, const int* __restrict__ ph,
        const int* __restrict__ pw, int n, const unsigned* __restrict__ h1,
        unsigned* __restrict__ h2a, unsigned* __restrict__ h2b,
        const unsigned* __restrict__ cache) {
    __shared__ unsigned psum[256];
    __shared__ unsigned res[8];
    __shared__ unsigned lha[NBIN];
    __shared__ unsigned lhb[NBIN];
    scan2048(h1, CA, NPRE, psum, res, 0);
    for (int b = threadIdx.x; b < NBIN; b += 256) { lha[b] = 0; lhb[b] = 0; }
    __syncthreads();
    unsigned binA = res[0], bin6 = res[2];
    float ih = (float)ph[0], iw = (float)pw[0];
    int stride = gridDim.x * 256;
    for (int i = blockIdx.x * 256 + threadIdx.x; i < n; i += stride) {
        unsigned inv = cache ? cache[i] : decode_inv(anchor[i], loc[i], ih, iw, score[i]);
        unsigned top = inv >> 21;
        if (top == binA) atomicAdd(&lha[(inv >> 10) & (NBIN - 1)], 1u);
        if (top == bin6) atomicAdd(&lhb[(inv >> 10) & (NBIN - 1)], 1u);
    }
    __syncthreads();
    for (int b = threadIdx.x; b < NBIN; b += 256) {
        unsigned ca = lha[b], cb = lhb[b];
        if (ca) atomicAdd(&h2a[b], ca);
        if (cb) atomicAdd(&h2b[b], cb);
    }
}

// two-phase compaction: block-local counts -> one atomicAdd per counter per block
__global__ void __launch_bounds__(256) k_compact(
        const float4* __restrict__ loc, const float* __restrict__ score,
        const float4* __restrict__ anchor, const int* __restrict__ ph,
        const int* __restrict__ pw, int n,
        const unsigned* __restrict__ h1, const unsigned* __restrict__ h2a,
        const unsigned* __restrict__ h2b,
        u64* __restrict__ candA, u64* __restrict__ cand6,
        unsigned* __restrict__ cnts, const unsigned* __restrict__ cache) {
    __shared__ unsigned psum[256];
    __shared__ unsigned res[12];
    int tid = threadIdx.x;
    // derive thresholds (same arithmetic as k_hist2's prologue -> identical bins)
    scan2048(h1, CA, NPRE, psum, res, 0);          // res[0]=binA res[1]=runA res[2]=bin6 res[3]=run6
    scan2048(h2a, CA - res[1], 0, psum, res, 4);   // res[4]=subA
    scan2048(h2b, NPRE - res[3], 0, psum, res, 8); // res[8]=sub6
    unsigned THA = res[0] * (unsigned)NBIN + res[4];
    unsigned TH6 = res[2] * (unsigned)NBIN + res[8];
    float ih = (float)ph[0], iw = (float)pw[0];
    int stride = gridDim.x * 256;
    // phase 1: count
    unsigned c6 = 0, cA = 0;
    for (int i = blockIdx.x * 256 + tid; i < n; i += stride) {
        unsigned inv = cache ? cache[i] : decode_inv(anchor[i], loc[i], ih, iw, score[i]);
        unsigned pre = inv >> 10;
        c6 += (pre <= TH6);
        cA += (pre <= THA);
    }
    psum[tid] = (cA << 16) | c6;
    __syncthreads();
    for (int off = 1; off < 256; off <<= 1) {
        unsigned v = (tid >= off) ? psum[tid - off] : 0u;
        __syncthreads();
        psum[tid] += v;
        __syncthreads();
    }
    if (tid == 0) {
        unsigned tot = psum[255];
        res[4] = atomicAdd(&cnts[1], tot & 0xFFFFu);
        res[5] = atomicAdd(&cnts[0], tot >> 16);
    }
    __syncthreads();
    unsigned excl = (tid == 0) ? 0u : psum[tid - 1];
    unsigned pos6 = res[4] + (excl & 0xFFFFu);
    unsigned posA = res[5] + (excl >> 16);
    // phase 2: write
    for (int i = blockIdx.x * 256 + tid; i < n; i += stride) {
        unsigned inv = cache ? cache[i] : decode_inv(anchor[i], loc[i], ih, iw, score[i]);
        unsigned pre = inv >> 10;
        if (pre <= TH6) {
            u64 key = ((u64)inv << 32) | (unsigned)i;
            if (pos6 < CAP6) cand6[pos6] = key;
            pos6++;
            if (pre <= THA) {
                if (posA < CAPA) candA[posA] = key;
                posA++;
            }
        }
    }
}

// exact global ranks of top-CA candidates (candA is prefix-closed in global order)
__global__ void __launch_bounds__(256) k_rankA(
        const u64* __restrict__ candA, const unsigned* __restrict__ cnts,
        unsigned* __restrict__ orderA) {
    __shared__ u64 lk[CAPA];
    int tid = threadIdx.x;
    int MA = (int)min(cnts[0], (unsigned)CAPA);
    for (int i = tid; i < CAPA; i += 256) lk[i] = (i < MA) ? candA[i] : ~0ULL;
    __syncthreads();
    int c = blockIdx.x * 256 + tid;
    if (c < MA) {
        u64 key = lk[c];
        int rank = 0;
#pragma unroll 8
        for (int j = 0; j < MA; ++j) rank += (lk[j] < key) ? 1 : 0;
        if (rank < CA) orderA[rank] = (unsigned)(key & 0xFFFFFFFFu);
    }
}

// suppression bit-matrix for top-CA candidates: bit j of word w of row i
__global__ void __launch_bounds__(256) k_mat(
        const float4* __restrict__ loc, const float4* __restrict__ anchor,
        const int* __restrict__ ph, const int* __restrict__ pw,
        const unsigned* __restrict__ orderA, u64* __restrict__ gmat, int n) {
    __shared__ float4 sroi[CA];
    __shared__ float sarea[CA];
    int tid = threadIdx.x;
    float ih = (float)ph[0], iw = (float)pw[0];
    for (int r = tid; r < CA; r += 256) {
        unsigned idx = orderA[r];
        float4 b = make_float4(0.f, 0.f, 0.f, 0.f);
        if (idx < (unsigned)n) b = decode_box(anchor[idx], loc[idx], ih, iw);
        sroi[r] = b;
        sarea[r] = (b.z - b.x) * (b.w - b.y);
    }
    __syncthreads();
    int row = blockIdx.x * 32 + (tid >> 3);
    int w   = tid & 7;
    float4 b = sroi[row];
    float ab = sarea[row];
    u64 bits = 0;
    int j0 = w * 64;
#pragma unroll 4
    for (int jj = 0; jj < 64; ++jj) {
        int j = j0 + jj;
        if (j > row) {
            float4 c = sroi[j];
            float yy1 = fmaxf(b.x, c.x);
            float xx1 = fmaxf(b.y, c.y);
            float yy2 = fminf(b.z, c.z);
            float xx2 = fminf(b.w, c.w);
            float inter = fmaxf(yy2 - yy1, 0.0f) * fmaxf(xx2 - xx1, 0.0f);
            float iou = inter / (ab + sarea[j] - inter);  // same op order as reference
            if (iou > NMS_T) bits |= (1ULL << jj);
        }
    }
    gmat[(size_t)row * 8 + w] = bits;
}

// serial scan over bitmask matrix; breaks at 300 kept (exact: suppression flows forward only)
__global__ void __launch_bounds__(256) k_scan_nms(
        const float4* __restrict__ loc, const float4* __restrict__ anchor,
        const int* __restrict__ ph, const int* __restrict__ pw,
        const unsigned* __restrict__ orderA, const u64* __restrict__ gmat,
        unsigned* __restrict__ cnts, float* __restrict__ out, int n) {
    __shared__ u64 smat[CA * 8];      // 32 KB
    __shared__ float4 sroi[CA];       // 8 KB
    __shared__ unsigned ssup[CA / 32];
    __shared__ unsigned skept[NPOST];
    int tid = threadIdx.x;
    if (tid < CA / 32) ssup[tid] = 0;
    __syncthreads();
    float ih = (float)ph[0], iw = (float)pw[0];
    for (int r = tid; r < CA; r += 256) {
        unsigned idx = orderA[r];
        float4 b = make_float4(0.f, 0.f, 0.f, 0.f);
        if (idx < (unsigned)n) b = decode_box(anchor[idx], loc[idx], ih, iw);
        sroi[r] = b;
        bool valid = ((b.z - b.x) >= MINSZ) && ((b.w - b.y) >= MINSZ);
        if (!valid) atomicOr(&ssup[r >> 5], 1u << (r & 31));
    }
    {   // stage matrix 32 KB, vectorized
        const float4* gm4 = (const float4*)gmat;
        float4* sm4 = (float4*)smat;
        for (int k = tid; k < CA * 8 * 8 / 16; k += 256) sm4[k] = gm4[k];
    }
    __syncthreads();
    if (tid >= 64) return;
    int lane = tid, w = lane & 7;
    u64 sup = ((u64)ssup[2 * w + 1] << 32) | (u64)ssup[2 * w];
    int Ceff = (int)min((unsigned)CA, cnts[0]);
    int nk = 0;
    u64 r0 = smat[0 * 8 + w];
    u64 r1 = smat[1 * 8 + w];
    for (int i = 0; i < Ceff; ++i) {
        u64 r2 = (i + 2 < CA) ? smat[(i + 2) * 8 + w] : 0ULL;   // 2-deep prefetch
        bool supbit = (lane == (i >> 6)) && ((sup >> (i & 63)) & 1ULL);
        if (__ballot(supbit) == 0ULL) {
            if (lane == 0) skept[nk] = (unsigned)i;
            sup |= r0;
            ++nk;
            if (nk == NPOST) break;
        }
        r0 = r1; r1 = r2;
    }
    float4* out4 = (float4*)out;
    for (int k = lane; k < NPOST; k += 64) {
        float4 o = make_float4(0.f, 0.f, 0.f, 0.f);
        if (k < nk) o = sroi[skept[k]];
        out4[k] = o;
    }
    if (lane == 0)
        cnts[2] = ((nk < NPOST && cnts[1] > (unsigned)Ceff) || cnts[0] > (unsigned)CAPA) ? 1u : 0u;
}

// flag-gated exact fallback: full 6000 rank + serial NMS. Never runs on sane data.
__global__ void __launch_bounds__(256) k_fb(
        const float4* __restrict__ loc, const float4* __restrict__ anchor,
        const int* __restrict__ ph, const int* __restrict__ pw,
        const u64* __restrict__ cand6, const unsigned* __restrict__ cnts,
        unsigned* __restrict__ order6, float4* __restrict__ roi6,
        float* __restrict__ out, int n) {
    if (cnts[2] == 0) return;
    __shared__ u64 lk[CAP6];          // 64 KB
    __shared__ float ky1[NPOST], kx1[NPOST], ky2[NPOST], kx2[NPOST], kar[NPOST];
    int tid = threadIdx.x;
    int M = (int)min(cnts[1], (unsigned)CAP6);
    for (int i = tid; i < CAP6; i += 256) lk[i] = (i < M) ? cand6[i] : ~0ULL;
    for (int r = tid; r < NPRE; r += 256) order6[r] = 0xFFFFFFFFu;
    __syncthreads();
    for (int c = tid; c < M; c += 256) {
        u64 key = lk[c];
        int rank = 0;
        for (int j = 0; j < M; ++j) rank += (lk[j] < key) ? 1 : 0;
        if (rank < NPRE) order6[rank] = (unsigned)(key & 0xFFFFFFFFu);
    }
    __syncthreads();
    float ih = (float)ph[0], iw = (float)pw[0];
    for (int r = tid; r < NPRE; r += 256) {
        unsigned idx = order6[r];
        float4 b = make_float4(0.f, 0.f, 0.f, 0.f);
        if (idx < (unsigned)n) b = decode_box(anchor[idx], loc[idx], ih, iw);
        roi6[r] = b;
    }
    __syncthreads();
    if (tid >= 64) return;
    int lane = tid;
    int nk = 0;
    for (int i = 0; i < NPRE; i++) {
        float4 b = roi6[i];
        float hs = b.z - b.x, wd = b.w - b.y;
        if (!(hs >= MINSZ && wd >= MINSZ)) continue;
        float ab = hs * wd;
        bool sup = false;
        for (int base = 0; base < nk && !sup; base += 64) {
            int t = base + lane;
            bool s = false;
            if (t < nk) {
                float yy1 = fmaxf(b.x, ky1[t]);
                float xx1 = fmaxf(b.y, kx1[t]);
                float yy2 = fminf(b.z, ky2[t]);
                float xx2 = fminf(b.w, kx2[t]);
                float inter = fmaxf(yy2 - yy1, 0.0f) * fmaxf(xx2 - xx1, 0.0f);
                float iou = inter / (kar[t] + ab - inter);
                s = iou > NMS_T;
            }
            sup = (__ballot(s) != 0ULL);
        }
        if (!sup) {
            if (lane == 0) { ky1[nk] = b.x; kx1[nk] = b.y; ky2[nk] = b.z; kx2[nk] = b.w; kar[nk] = ab; }
            nk++;
            if (nk == NPOST) break;
        }
    }
    for (int k = lane; k < NPOST; k += 64) {
        float4 o = make_float4(0.f, 0.f, 0.f, 0.f);
        if (k < nk) o = make_float4(ky1[k], kx1[k], ky2[k], kx2[k]);
        reinterpret_cast<float4*>(out)[k] = o;
    }
}

extern "C" void kernel_launch(void* const* d_in, const int* in_sizes, int n_in,
                              void* d_out, int out_size, void* d_ws, size_t ws_size,
                              hipStream_t stream) {
    const float4* loc    = (const float4*)d_in[0];
    const float*  score  = (const float*)d_in[1];
    const float4* anchor = (const float4*)d_in[2];
    const int*    ph     = (const int*)d_in[3];
    const int*    pw     = (const int*)d_in[4];
    int n = in_sizes[1];

    char* ws = (char*)d_ws;
    u64*      cand6  = (u64*)(ws + OFF_CAND6);
    u64*      candA  = (u64*)(ws + OFF_CANDA);
    unsigned* orderA = (unsigned*)(ws + OFF_ORDERA);
    unsigned* order6 = (unsigned*)(ws + OFF_ORDER6);
    float4*   roi6   = (float4*)(ws + OFF_ROI6);
    unsigned* h1     = (unsigned*)(ws + OFF_H1);
    unsigned* h2a    = (unsigned*)(ws + OFF_H2A);
    unsigned* h2b    = (unsigned*)(ws + OFF_H2B);
    unsigned* cnts   = (unsigned*)(ws + OFF_CNT);
    u64*      gmat   = (u64*)(ws + OFF_GMAT);
    unsigned* cache  = nullptr;
    if (ws_size >= (size_t)OFF_KEYS + (size_t)n * 4) cache = (unsigned*)(ws + OFF_KEYS);

    float* out = (float*)d_out;

    k_init    <<<dim3(28),  dim3(256), 0, stream>>>(h1, orderA);   // zeroes h1..cnts (contiguous)
    k_hist1   <<<dim3(1024), dim3(256), 0, stream>>>(loc, score, anchor, ph, pw, n, h1, cache);
    k_hist2   <<<dim3(256), dim3(256), 0, stream>>>(loc, score, anchor, ph, pw, n, h1, h2a, h2b, cache);
    k_compact <<<dim3(256), dim3(256), 0, stream>>>(loc, score, anchor, ph, pw, n, h1, h2a, h2b,
                                                    candA, cand6, cnts, cache);
    k_rankA   <<<dim3(CAPA / 256), dim3(256), 0, stream>>>(candA, cnts, orderA);
    k_mat     <<<dim3(CA / 32),    dim3(256), 0, stream>>>(loc, anchor, ph, pw, orderA, gmat, n);
    k_scan_nms<<<dim3(1),   dim3(256), 0, stream>>>(loc, anchor, ph, pw, orderA, gmat, cnts, out, n);
    k_fb      <<<dim3(1),   dim3(256), 0, stream>>>(loc, anchor, ph, pw, cand6, cnts, order6, roi6, out, n);
}